// Round 6
// baseline (151.678 us; speedup 1.0000x reference)
//
#include <hip/hip_runtime.h>
#include <math.h>

#define INV_B (1.0f / 8192.0f)

typedef float  v2f  __attribute__((ext_vector_type(2)));
typedef _Float16 half8 __attribute__((ext_vector_type(8)));
typedef float  f32x4 __attribute__((ext_vector_type(4)));

// ---------------------------------------------------------------------------
// Compile-time GF(2) tracking of the CNOT network (R3-verified, absmax 0.0).
// Index i (8 bits): wire w <-> bit (7-w).  Storage: i = 4*lane + reg.
// ---------------------------------------------------------------------------
struct QTables {
    int xm[6][8];   // xor (partner) mask per (layer, wire)
    int rm[6][8];   // row parity mask per (layer, wire)
    int meas[4];    // measurement parity masks, wires 0..3
};
constexpr QTables make_tables() {
    QTables T{};
    int Mrow[8] = {}, Ncol[8] = {};
    for (int b = 0; b < 8; ++b) { Mrow[b] = 1 << b; Ncol[b] = 1 << b; }
    constexpr int bc[11] = {7,6,5,4,3,2,1,0,7,5,3};
    constexpr int bt[11] = {6,5,4,3,2,1,0,7,5,3,1};
    for (int l = 0; l < 6; ++l) {
        for (int w = 0; w < 8; ++w) { T.xm[l][w] = Ncol[7 - w]; T.rm[l][w] = Mrow[7 - w]; }
        for (int k = 0; k < 11; ++k) { Mrow[bt[k]] ^= Mrow[bc[k]]; Ncol[bc[k]] ^= Ncol[bt[k]]; }
    }
    for (int w = 0; w < 4; ++w) T.meas[w] = Mrow[7 - w];
    return T;
}
constexpr QTables TB = make_tables();

// xor-shuffle along lane mask ML: 1..3 DPP quad_perm (VALU pipe),
// 4..31 ds_swizzle (LDS pipe, immediate offset), >=32 ds_bpermute.
template<int ML>
static __device__ __forceinline__ float lanex(float v) {
    if constexpr (ML == 0) { return v; }
    else if constexpr (ML == 1) { return __int_as_float(__builtin_amdgcn_update_dpp(0, __float_as_int(v), 0xB1, 0xF, 0xF, true)); }
    else if constexpr (ML == 2) { return __int_as_float(__builtin_amdgcn_update_dpp(0, __float_as_int(v), 0x4E, 0xF, 0xF, true)); }
    else if constexpr (ML == 3) { return __int_as_float(__builtin_amdgcn_update_dpp(0, __float_as_int(v), 0x1B, 0xF, 0xF, true)); }
    else if constexpr (ML < 32) { return __int_as_float(__builtin_amdgcn_ds_swizzle(__float_as_int(v), 0x1F | (ML << 10))); }
    else { return __shfl_xor(v, ML, 64); }
}

static __device__ __forceinline__ float bsum64(float v) {
    v += lanex<1>(v);  v += lanex<2>(v);
    v += lanex<4>(v);  v += lanex<8>(v);
    v += lanex<16>(v); v += __shfl_xor(v, 32, 64);
    return v;
}

static __device__ __forceinline__ float tanh_fast(float v) {
    const float c = fminf(fmaxf(v, -10.f), 10.f);
    const float e = __expf(2.f * c);
    return (e - 1.f) / (e + 1.f);
}

// Fused SU(2) gate, packed complex, TWO rows per wave (z[0..3]=row A,
// z[4..7]=row B; identical lane/reg index algebra per row).  R3-verified math.
template<int XM, int RM>
static __device__ __forceinline__ void gate2(v2f (&z)[8], const int lane,
                                             const float u00r, const float u00i,
                                             const float u01r, const float u01i) {
    constexpr int ML = XM >> 2, MR = XM & 3;
    constexpr int RL = RM >> 2, RR = RM & 3;
    const int pl = __popc(lane & RL) & 1;
    const float csi0 = pl ? -u00i : u00i;
    const float cpr0 = pl ? -u01r : u01r;
    const float csi1 = -csi0, cpr1 = -cpr0;
    v2f p[8];
    #pragma unroll
    for (int rr = 0; rr < 8; ++rr) {
        const int src = (rr & 4) | ((rr & 3) ^ MR);
        p[rr].x = lanex<ML>(z[src].x);
        p[rr].y = lanex<ML>(z[src].y);
    }
    #pragma unroll
    for (int rr = 0; rr < 8; ++rr) {
        const int pb = __builtin_popcount(rr & RR) & 1;   // folds at compile time
        const float csi = pb ? csi1 : csi0;
        const float cpr = pb ? cpr1 : cpr0;
        const v2f zs = { -z[rr].y, z[rr].x };
        const v2f ps = { -p[rr].y, p[rr].x };
        z[rr] = ((u00r * z[rr] + csi * zs) + cpr * p[rr]) + u01i * ps;
    }
}

// ---------------------------------------------------------------------------
// k_feat: cf = tanh(relu(x@fW1.T+fb1)@fW2.T+fb2) via MFMA f16 16x16x32
// (fp32 accum).  Also builds the 48 fused unitaries (block 0) and zeros the
// BN accumulators + spin counter.  Grid: 128 x 256.  (R5-verified)
// ---------------------------------------------------------------------------
#define XS 264   // padded LDS stride in halves (528B, 16B-divisible)
__global__ __launch_bounds__(256) void k_feat(
        const float* __restrict__ x, const float* __restrict__ qw,
        const float* __restrict__ fW1, const float* __restrict__ fb1,
        const float* __restrict__ fW2, const float* __restrict__ fb2,
        float* __restrict__ U, float* __restrict__ cfws, float* __restrict__ accz) {
    const int t = threadIdx.x, b = blockIdx.x;

    if (t < 16) accz[b * 16 + t] = 0.f;          // zeros ws[0..2048): acc1, acc2, cnt
    if (b == 0 && t < 48) {
        const int l = t >> 3, q = t & 7;
        const float* a = qw + l * 24 + q * 3;
        const float h1 = 0.5f * a[0], h2 = 0.5f * a[1], h3 = 0.5f * a[2];
        const float c1 = cosf(h1), s1 = sinf(h1);
        const float c2 = cosf(h2), s2 = sinf(h2);
        const float c3 = cosf(h3), s3 = sinf(h3);
        const float m00r =  c1 * c2, m00i =  s1 * s2;   // (Ry*Rx) row 0
        const float m01r = -c1 * s2, m01i = -s1 * c2;
        float4 u;
        u.x = m00r * c3 + m00i * s3;  u.y = m00i * c3 - m00r * s3;   // u00 e^{-i h3}
        u.z = m01r * c3 + m01i * s3;  u.w = m01i * c3 - m01r * s3;   // u01 e^{-i h3}
        ((float4*)U)[t] = u;
    }

    __shared__ _Float16 xl[64 * XS];   // x tile (rows = batch), f16
    __shared__ _Float16 wl[64 * XS];   // fW1 (rows = j), f16
    const long r0 = (long)b * 64;
    #pragma unroll
    for (int i = 0; i < 16; ++i) {
        const int idx = i * 256 + t;
        const int row = idx >> 6, c4 = idx & 63;
        const float4 xv = ((const float4*)(x + (r0 + row) * 256))[c4];
        _Float16* d = &xl[row * XS + c4 * 4];
        d[0] = (_Float16)xv.x; d[1] = (_Float16)xv.y;
        d[2] = (_Float16)xv.z; d[3] = (_Float16)xv.w;
        const float4 wv = ((const float4*)(fW1 + (long)row * 256))[c4];
        _Float16* e = &wl[row * XS + c4 * 4];
        e[0] = (_Float16)wv.x; e[1] = (_Float16)wv.y;
        e[2] = (_Float16)wv.z; e[3] = (_Float16)wv.w;
    }
    __syncthreads();

    const int lane = t & 63, w4 = t >> 6;
    const int g = lane >> 4, col = lane & 15;
    const int rloc = w4 * 16 + col;            // local batch row (B-frag n-index)

    half8 bf[8];                               // B frags: k = kb*32 + g*8 + jj
    #pragma unroll
    for (int kb = 0; kb < 8; ++kb)
        bf[kb] = *(const half8*)&xl[rloc * XS + kb * 32 + g * 8];

    float accc[4] = {0.f, 0.f, 0.f, 0.f};
    #pragma unroll
    for (int jc = 0; jc < 4; ++jc) {
        f32x4 cv = {0.f, 0.f, 0.f, 0.f};
        #pragma unroll
        for (int kb = 0; kb < 8; ++kb) {
            const half8 af = *(const half8*)&wl[(jc * 16 + col) * XS + kb * 32 + g * 8];
            cv = __builtin_amdgcn_mfma_f32_16x16x32_f16(af, bf[kb], cv, 0, 0, 0);
        }
        #pragma unroll
        for (int r = 0; r < 4; ++r) {
            const int j = jc * 16 + g * 4 + r;
            const float z = fmaxf(cv[r] + fb1[j], 0.f);
            #pragma unroll
            for (int c = 0; c < 4; ++c) accc[c] += z * fW2[c * 64 + j];
        }
    }
    #pragma unroll
    for (int c = 0; c < 4; ++c) {
        accc[c] += __shfl_xor(accc[c], 16, 64);
        accc[c] += __shfl_xor(accc[c], 32, 64);
    }
    if (g == 0) {
        float4 o;
        o.x = tanh_fast(accc[0] + fb2[0]);
        o.y = tanh_fast(accc[1] + fb2[1]);
        o.z = tanh_fast(accc[2] + fb2[2]);
        o.w = tanh_fast(accc[3] + fb2[3]);
        ((float4*)cfws)[r0 + w4 * 16 + col] = o;
    }
}

// ---------------------------------------------------------------------------
// k_main: quantum circuit, TWO rows per wave (ILP=2 over the 48-gate chain;
// U loads shared).  Grid: 1024 blocks x 256 thr (8 rows/block).
// ---------------------------------------------------------------------------
__global__ __launch_bounds__(256) void k_main(
        const float* __restrict__ x, const float* __restrict__ U,
        const float* __restrict__ cfws,
        const float* __restrict__ aW, const float* __restrict__ ab,
        float* __restrict__ hws, float* __restrict__ acc1) {
    const int t = threadIdx.x, lane = t & 63, wv = t >> 6;
    const int b = blockIdx.x;
    const int rowA = b * 8 + wv * 2, rowB = rowA + 1;

    const float4 xa = ((const float4*)(x + (long)rowA * 256))[lane];
    const float4 xb = ((const float4*)(x + (long)rowB * 256))[lane];
    const float4 cfa = ((const float4*)cfws)[rowA];      // prefetch: retires
    const float4 cfb = ((const float4*)cfws)[rowB];      // under the circuit

    v2f z[8] = { {xa.x, 0.f}, {xa.y, 0.f}, {xa.z, 0.f}, {xa.w, 0.f},
                 {xb.x, 0.f}, {xb.y, 0.f}, {xb.z, 0.f}, {xb.w, 0.f} };
    const float4* U4 = (const float4*)U;

#define GATE(L, W) { const float4 u = U4[(L) * 8 + (W)]; \
                     gate2<TB.xm[L][W], TB.rm[L][W]>(z, lane, u.x, u.y, u.z, u.w); }
#define LAYER(L) GATE(L,0) GATE(L,1) GATE(L,2) GATE(L,3) GATE(L,4) GATE(L,5) GATE(L,6) GATE(L,7)
    LAYER(0) LAYER(1) LAYER(2) LAYER(3) LAYER(4) LAYER(5)
#undef LAYER
#undef GATE

    // probabilities + Z expectations per row (normalization folded into qe)
    float hA[4], hB[4];
    #pragma unroll
    for (int half = 0; half < 2; ++half) {
        float pv[4];
        #pragma unroll
        for (int r = 0; r < 4; ++r) {
            const v2f zz = z[half * 4 + r];
            pv[r] = zz.x * zz.x + zz.y * zz.y;
        }
        float S = pv[0] + pv[1] + pv[2] + pv[3];
        float qs[4];
        #pragma unroll
        for (int w = 0; w < 4; ++w) {
            const int mm = TB.meas[w];
            const int plm = __popc(lane & (mm >> 2)) & 1;
            float s = 0.f;
            #pragma unroll
            for (int r = 0; r < 4; ++r) {
                const int sgn = plm ^ (__builtin_popcount(r & (mm & 3)) & 1);
                s += sgn ? -pv[r] : pv[r];
            }
            qs[w] = s;
        }
        S = bsum64(S);
        const float inv = 1.0f / S;
        float qe[4];
        #pragma unroll
        for (int w = 0; w < 4; ++w) qe[w] = bsum64(qs[w]) * inv;

        const float4 cfv = half ? cfb : cfa;
        const float cf[4] = {cfv.x, cfv.y, cfv.z, cfv.w};
        float* h = half ? hB : hA;
        #pragma unroll
        for (int k = 0; k < 4; ++k) {
            float s = ab[k] + cf[k];
            #pragma unroll
            for (int j = 0; j < 4; ++j) s += aW[k * 4 + j] * qe[j];
            h[k] = s;
        }
    }
    if (lane == 0) {
        ((float4*)hws)[rowA] = make_float4(hA[0], hA[1], hA[2], hA[3]);
        ((float4*)hws)[rowB] = make_float4(hB[0], hB[1], hB[2], hB[3]);
    }

    __shared__ float wsum[8][20];
    if (lane < 20) {
        const int j = (lane - 4) >> 2, k = (lane - 4) & 3;
        wsum[wv * 2 + 0][lane] = (lane < 4) ? hA[lane] : hA[j] * hA[k];
        wsum[wv * 2 + 1][lane] = (lane < 4) ? hB[lane] : hB[j] * hB[k];
    }
    __syncthreads();
    if (t < 20) {
        float v = 0.f;
        #pragma unroll
        for (int i = 0; i < 8; ++i) v += wsum[i][t];
        atomicAdd(acc1 + (b & 31) * 20 + t, v);
    }
}

// ---------------------------------------------------------------------------
// k_tail: analytic BN1 + relu + layer2 -> z2 (regs) + z2 stats atomics,
// then device-scope arrive-counter barrier (128 blocks <= 256 CUs: all
// co-resident -> spin is safe), then BN2 + layer3(relu) + layer4 + sigmoid.
// Grid: 128 x 64, one row per thread; z2 never leaves registers.
// ---------------------------------------------------------------------------
__global__ __launch_bounds__(64) void k_tail(
        const float* __restrict__ hws, const float* __restrict__ acc1,
        const float* __restrict__ cW1, const float* __restrict__ cb1,
        const float* __restrict__ g1, const float* __restrict__ be1,
        const float* __restrict__ cW2, const float* __restrict__ cb2,
        const float* __restrict__ g2, const float* __restrict__ be2,
        const float* __restrict__ cW3, const float* __restrict__ cb3,
        const float* __restrict__ cW4, const float* __restrict__ cb4,
        float* __restrict__ acc2, int* __restrict__ cnt,
        float* __restrict__ out) {
    const int t = threadIdx.x;
    __shared__ float sA[20];
    __shared__ float m1s[32], is1[32];
    if (t < 20) {
        float s = 0.f;
        for (int sl = 0; sl < 32; ++sl) s += acc1[sl * 20 + t];
        sA[t] = s;
    }
    __syncthreads();
    if (t < 32) {
        float mu[4], w[4];
        #pragma unroll
        for (int k = 0; k < 4; ++k) mu[k] = sA[k] * INV_B;
        float m = cb1[t];
        #pragma unroll
        for (int k = 0; k < 4; ++k) { w[k] = cW1[t * 4 + k]; m += w[k] * mu[k]; }
        float var = 0.f;
        #pragma unroll
        for (int a2 = 0; a2 < 4; ++a2)
            #pragma unroll
            for (int b2 = 0; b2 < 4; ++b2)
                var += w[a2] * w[b2] * (sA[4 + a2 * 4 + b2] * INV_B - mu[a2] * mu[b2]);
        m1s[t] = m;
        is1[t] = 1.0f / sqrtf(var + 1e-5f);
    }
    __syncthreads();

    const long e = (long)blockIdx.x * 64 + t;
    const float4 h4 = ((const float4*)hws)[e];
    const float h[4] = {h4.x, h4.y, h4.z, h4.w};
    float a1[32];
    #pragma unroll
    for (int j = 0; j < 32; ++j) {
        float zz = cb1[j];
        #pragma unroll
        for (int k = 0; k < 4; ++k) zz += cW1[j * 4 + k] * h[k];
        a1[j] = fmaxf((zz - m1s[j]) * is1[j] * g1[j] + be1[j], 0.f);
    }
    float z2[16];
    #pragma unroll
    for (int k = 0; k < 16; ++k) {
        float s = cb2[k];
        #pragma unroll
        for (int j = 0; j < 32; ++j) s += cW2[k * 32 + j] * a1[j];
        z2[k] = s;
    }

    float sv[16], sq[16];
    #pragma unroll
    for (int k = 0; k < 16; ++k) { sv[k] = z2[k]; sq[k] = z2[k] * z2[k]; }
    #pragma unroll
    for (int m = 1; m < 64; m <<= 1) {
        #pragma unroll
        for (int k = 0; k < 16; ++k) {
            sv[k] += __shfl_xor(sv[k], m, 64);
            sq[k] += __shfl_xor(sq[k], m, 64);
        }
    }
    if (t == 0) {
        float* dst = acc2 + ((int)blockIdx.x & 31) * 32;
        #pragma unroll
        for (int k = 0; k < 16; ++k) atomicAdd(dst + k, sv[k]);
        #pragma unroll
        for (int k = 0; k < 16; ++k) atomicAdd(dst + 16 + k, sq[k]);
        __threadfence();
        __hip_atomic_fetch_add(cnt, 1, __ATOMIC_ACQ_REL, __HIP_MEMORY_SCOPE_AGENT);
        while (__hip_atomic_load(cnt, __ATOMIC_ACQUIRE, __HIP_MEMORY_SCOPE_AGENT)
               < (int)gridDim.x) { __builtin_amdgcn_s_sleep(2); }
    }
    __syncthreads();

    __shared__ float m2s[16], is2[16];
    if (t < 32) {
        float s = 0.f;
        for (int sl = 0; sl < 32; ++sl)
            s += __hip_atomic_load(acc2 + sl * 32 + t, __ATOMIC_RELAXED,
                                   __HIP_MEMORY_SCOPE_AGENT);
        sA[t < 20 ? t : 0] = 0.f;   // dummy to keep sA live; real store below
        if (t < 16) { /* mean slots 0..15 */ }
        __shared__ float sB[32];
        sB[t] = s;
        __syncthreads();
        if (t < 16) {
            const float m = sB[t] * INV_B;
            m2s[t] = m;
            is2[t] = 1.0f / sqrtf(sB[16 + t] * INV_B - m * m + 1e-5f);
        }
    }
    __syncthreads();

    float a2[16];
    #pragma unroll
    for (int k = 0; k < 16; ++k)
        a2[k] = fmaxf((z2[k] - m2s[k]) * is2[k] * g2[k] + be2[k], 0.f);
    float z3[8];
    #pragma unroll
    for (int j = 0; j < 8; ++j) {
        float s = cb3[j];
        #pragma unroll
        for (int k = 0; k < 16; ++k) s += cW3[j * 16 + k] * a2[k];
        z3[j] = fmaxf(s, 0.f);
    }
    float y = cb4[0];
    #pragma unroll
    for (int j = 0; j < 8; ++j) y += cW4[j] * z3[j];
    out[e] = 1.0f / (1.0f + expf(-y));
}

// ---------------------------------------------------------------------------
extern "C" void kernel_launch(void* const* d_in, const int* in_sizes, int n_in,
                              void* d_out, int out_size, void* d_ws, size_t ws_size,
                              hipStream_t stream) {
    (void)in_sizes; (void)n_in; (void)out_size; (void)ws_size;
    const float* x   = (const float*)d_in[0];
    const float* qw  = (const float*)d_in[1];
    const float* aW  = (const float*)d_in[2];
    const float* ab  = (const float*)d_in[3];
    const float* fW1 = (const float*)d_in[4];
    const float* fb1 = (const float*)d_in[5];
    const float* fW2 = (const float*)d_in[6];
    const float* fb2 = (const float*)d_in[7];
    const float* cW1 = (const float*)d_in[8];
    const float* cb1 = (const float*)d_in[9];
    const float* g1  = (const float*)d_in[10];
    const float* be1 = (const float*)d_in[11];
    const float* cW2 = (const float*)d_in[12];
    const float* cb2 = (const float*)d_in[13];
    const float* g2  = (const float*)d_in[14];
    const float* be2 = (const float*)d_in[15];
    const float* cW3 = (const float*)d_in[16];
    const float* cb3 = (const float*)d_in[17];
    const float* cW4 = (const float*)d_in[18];
    const float* cb4 = (const float*)d_in[19];

    float* ws   = (float*)d_ws;
    float* acc1 = ws;               // 32 slots x 20 = 640   (zeroed by k_feat)
    int*   cnt  = (int*)(ws + 640); // arrive counter        (zeroed by k_feat)
    float* acc2 = ws + 1024;        // 32 slots x 32 = 1024  (zeroed by k_feat)
    float* U    = ws + 2048;        // 48 x 4
    float* cfws = ws + 4096;        // 8192 x 4
    float* hws  = ws + 40960;       // 8192 x 4

    k_feat<<<128, 256, 0, stream>>>(x, qw, fW1, fb1, fW2, fb2, U, cfws, ws);
    k_main<<<1024, 256, 0, stream>>>(x, U, cfws, aW, ab, hws, acc1);
    k_tail<<<128, 64, 0, stream>>>(hws, acc1, cW1, cb1, g1, be1, cW2, cb2,
                                   g2, be2, cW3, cb3, cW4, cb4, acc2, cnt,
                                   (float*)d_out);
}

// Round 7
// 137.732 us; speedup vs baseline: 1.1013x; 1.1013x over previous
//
#include <hip/hip_runtime.h>
#include <math.h>

#define INV_B (1.0f / 8192.0f)

typedef float  v2f  __attribute__((ext_vector_type(2)));
typedef _Float16 half8 __attribute__((ext_vector_type(8)));
typedef float  f32x4 __attribute__((ext_vector_type(4)));

// ---------------------------------------------------------------------------
// Compile-time GF(2) tracking of the CNOT network (R3-verified, absmax 0.0).
// Index i (8 bits): wire w <-> bit (7-w).  Storage: i = 4*lane + reg.
// ---------------------------------------------------------------------------
struct QTables {
    int xm[6][8];   // xor (partner) mask per (layer, wire)
    int rm[6][8];   // row parity mask per (layer, wire)
    int meas[4];    // measurement parity masks on storage index, wires 0..3
};
constexpr QTables make_tables() {
    QTables T{};
    int Mrow[8] = {}, Ncol[8] = {};
    for (int b = 0; b < 8; ++b) { Mrow[b] = 1 << b; Ncol[b] = 1 << b; }
    constexpr int bc[11] = {7,6,5,4,3,2,1,0,7,5,3};
    constexpr int bt[11] = {6,5,4,3,2,1,0,7,5,3,1};
    for (int l = 0; l < 6; ++l) {
        for (int w = 0; w < 8; ++w) { T.xm[l][w] = Ncol[7 - w]; T.rm[l][w] = Mrow[7 - w]; }
        for (int k = 0; k < 11; ++k) { Mrow[bt[k]] ^= Mrow[bc[k]]; Ncol[bc[k]] ^= Ncol[bt[k]]; }
    }
    for (int w = 0; w < 4; ++w) T.meas[w] = Mrow[7 - w];
    return T;
}
constexpr QTables TB = make_tables();

// xor-shuffle along lane mask ML: 1..3 DPP quad_perm (VALU pipe),
// 4..31 ds_swizzle (LDS pipe, immediate offset), >=32 shfl (bpermute).
template<int ML>
static __device__ __forceinline__ float lanex(float v) {
    if constexpr (ML == 0) { return v; }
    else if constexpr (ML == 1) { return __int_as_float(__builtin_amdgcn_update_dpp(0, __float_as_int(v), 0xB1, 0xF, 0xF, true)); }
    else if constexpr (ML == 2) { return __int_as_float(__builtin_amdgcn_update_dpp(0, __float_as_int(v), 0x4E, 0xF, 0xF, true)); }
    else if constexpr (ML == 3) { return __int_as_float(__builtin_amdgcn_update_dpp(0, __float_as_int(v), 0x1B, 0xF, 0xF, true)); }
    else if constexpr (ML < 32) { return __int_as_float(__builtin_amdgcn_ds_swizzle(__float_as_int(v), 0x1F | (ML << 10))); }
    else { return __shfl_xor(v, ML, 64); }
}

static __device__ __forceinline__ float tanh_fast(float v) {
    const float c = fminf(fmaxf(v, -10.f), 10.f);
    const float e = __expf(2.f * c);
    return (e - 1.f) / (e + 1.f);
}

// Fused SU(2) gate, packed complex (R3/R5-verified math).
template<int XM, int RM>
static __device__ __forceinline__ void gate(v2f (&z)[4], const int lane,
                                            const float u00r, const float u00i,
                                            const float u01r, const float u01i) {
    constexpr int ML = XM >> 2, MR = XM & 3;
    constexpr int RL = RM >> 2, RR = RM & 3;
    const int pl = __popc(lane & RL) & 1;
    const float csi0 = pl ? -u00i : u00i;
    const float cpr0 = pl ? -u01r : u01r;
    const float csi1 = -csi0, cpr1 = -cpr0;
    v2f p[4];
    #pragma unroll
    for (int r = 0; r < 4; ++r) {
        p[r].x = lanex<ML>(z[r ^ MR].x);
        p[r].y = lanex<ML>(z[r ^ MR].y);
    }
    #pragma unroll
    for (int r = 0; r < 4; ++r) {
        const int pb = __builtin_popcount(r & RR) & 1;
        const float csi = pb ? csi1 : csi0;
        const float cpr = pb ? cpr1 : cpr0;
        const v2f zs = { -z[r].y, z[r].x };
        const v2f ps = { -p[r].y, p[r].x };
        z[r] = ((u00r * z[r] + csi * zs) + cpr * p[r]) + u01i * ps;
    }
}

// ---------------------------------------------------------------------------
// k_pre: blocks 0..127  = MLP cf via MFMA (R5-verified) + zero accumulators.
//        blocks 128..191 = build the circuit operator W: evolve 256 basis
//        states exactly (fp32), store Wt[i][k] f16, i-major (rows 0..255 = re,
//        256..511 = im) -> B-fragment-ready for k_gemm.
// ---------------------------------------------------------------------------
#define XS 264   // padded LDS stride in halves (528B, 16B-divisible)
__global__ __launch_bounds__(256) void k_pre(
        const float* __restrict__ x, const float* __restrict__ qw,
        const float* __restrict__ fW1, const float* __restrict__ fb1,
        const float* __restrict__ fW2, const float* __restrict__ fb2,
        _Float16* __restrict__ Wt, float* __restrict__ cfws,
        float* __restrict__ accz) {
    const int t = threadIdx.x, b = blockIdx.x;

    if (b >= 128) {
        // ---- operator build: 64 blocks x 4 waves = 256 basis states
        __shared__ float4 Us[48];
        if (t < 48) {
            const int l = t >> 3, q = t & 7;
            const float* a = qw + l * 24 + q * 3;
            const float h1 = 0.5f * a[0], h2 = 0.5f * a[1], h3 = 0.5f * a[2];
            const float c1 = cosf(h1), s1 = sinf(h1);
            const float c2 = cosf(h2), s2 = sinf(h2);
            const float c3 = cosf(h3), s3 = sinf(h3);
            const float m00r =  c1 * c2, m00i =  s1 * s2;   // (Ry*Rx) row 0
            const float m01r = -c1 * s2, m01i = -s1 * c2;
            float4 u;
            u.x = m00r * c3 + m00i * s3;  u.y = m00i * c3 - m00r * s3;  // u00 e^{-i h3}
            u.z = m01r * c3 + m01i * s3;  u.w = m01i * c3 - m01r * s3;  // u01 e^{-i h3}
            Us[t] = u;
        }
        __syncthreads();
        const int lane = t & 63, wv = t >> 6;
        const int k = (b - 128) * 4 + wv;          // basis state index
        v2f z[4];
        #pragma unroll
        for (int r = 0; r < 4; ++r) {
            z[r].x = (4 * lane + r == k) ? 1.f : 0.f;
            z[r].y = 0.f;
        }
#define GATE(L, W) { const float4 u = Us[(L) * 8 + (W)]; \
                     gate<TB.xm[L][W], TB.rm[L][W]>(z, lane, u.x, u.y, u.z, u.w); }
#define LAYER(L) GATE(L,0) GATE(L,1) GATE(L,2) GATE(L,3) GATE(L,4) GATE(L,5) GATE(L,6) GATE(L,7)
        LAYER(0) LAYER(1) LAYER(2) LAYER(3) LAYER(4) LAYER(5)
#undef LAYER
#undef GATE
        #pragma unroll
        for (int r = 0; r < 4; ++r) {
            const int i = 4 * lane + r;            // storage index
            Wt[(long)i * 256 + k]         = (_Float16)z[r].x;
            Wt[(long)(256 + i) * 256 + k] = (_Float16)z[r].y;
        }
        return;
    }

    // ---- MLP path (R5-verified)
    if (t < 16) accz[b * 16 + t] = 0.f;            // zero acc1+acc2 (2048 floats)

    __shared__ _Float16 xl[64 * XS];   // x tile (rows = batch), f16
    __shared__ _Float16 wl[64 * XS];   // fW1 (rows = j), f16
    const long r0 = (long)b * 64;
    #pragma unroll
    for (int i = 0; i < 16; ++i) {
        const int idx = i * 256 + t;
        const int row = idx >> 6, c4 = idx & 63;
        const float4 xv = ((const float4*)(x + (r0 + row) * 256))[c4];
        _Float16* d = &xl[row * XS + c4 * 4];
        d[0] = (_Float16)xv.x; d[1] = (_Float16)xv.y;
        d[2] = (_Float16)xv.z; d[3] = (_Float16)xv.w;
        const float4 wv2 = ((const float4*)(fW1 + (long)row * 256))[c4];
        _Float16* e = &wl[row * XS + c4 * 4];
        e[0] = (_Float16)wv2.x; e[1] = (_Float16)wv2.y;
        e[2] = (_Float16)wv2.z; e[3] = (_Float16)wv2.w;
    }
    __syncthreads();

    const int lane = t & 63, w4 = t >> 6;
    const int g = lane >> 4, col = lane & 15;
    const int rloc = w4 * 16 + col;

    half8 bf[8];
    #pragma unroll
    for (int kb = 0; kb < 8; ++kb)
        bf[kb] = *(const half8*)&xl[rloc * XS + kb * 32 + g * 8];

    float accc[4] = {0.f, 0.f, 0.f, 0.f};
    #pragma unroll
    for (int jc = 0; jc < 4; ++jc) {
        f32x4 cv = {0.f, 0.f, 0.f, 0.f};
        #pragma unroll
        for (int kb = 0; kb < 8; ++kb) {
            const half8 af = *(const half8*)&wl[(jc * 16 + col) * XS + kb * 32 + g * 8];
            cv = __builtin_amdgcn_mfma_f32_16x16x32_f16(af, bf[kb], cv, 0, 0, 0);
        }
        #pragma unroll
        for (int r = 0; r < 4; ++r) {
            const int j = jc * 16 + g * 4 + r;
            const float z = fmaxf(cv[r] + fb1[j], 0.f);
            #pragma unroll
            for (int c = 0; c < 4; ++c) accc[c] += z * fW2[c * 64 + j];
        }
    }
    #pragma unroll
    for (int c = 0; c < 4; ++c) {
        accc[c] += __shfl_xor(accc[c], 16, 64);
        accc[c] += __shfl_xor(accc[c], 32, 64);
    }
    if (g == 0) {
        float4 o;
        o.x = tanh_fast(accc[0] + fb2[0]);
        o.y = tanh_fast(accc[1] + fb2[1]);
        o.z = tanh_fast(accc[2] + fb2[2]);
        o.w = tanh_fast(accc[3] + fb2[3]);
        ((float4*)cfws)[r0 + w4 * 16 + col] = o;
    }
}

// ---------------------------------------------------------------------------
// k_gemm: quantum output via S = X @ Wt^T (f16 MFMA, fp32 accum), fused
// |amp|^2 + sign-masked sums + h + BN1 moment atomics.
// 256 blocks x 128 thr (2 waves); block = 32 batch rows, wave = 16.
// Frag maps (R5-verified): A[m=lane&15][k=quad*8+j], B[k][n=lane&15],
// D col=lane&15 (n = W column i), row=quad*4+r (m = batch row).
// ---------------------------------------------------------------------------
__global__ __launch_bounds__(128) void k_gemm(
        const float* __restrict__ x, const _Float16* __restrict__ Wt,
        const float* __restrict__ cfws,
        const float* __restrict__ aW, const float* __restrict__ ab,
        float* __restrict__ hws, float* __restrict__ acc1) {
    const int t = threadIdx.x;
    const int lane = t & 63, w = t >> 6;
    const int col = lane & 15, quad = lane >> 4;
    const int R0 = blockIdx.x * 32;

    __shared__ _Float16 xa[32 * XS];
    #pragma unroll
    for (int i = 0; i < 16; ++i) {
        const int idx = i * 128 + t;
        const int row = idx >> 6, c4 = idx & 63;
        const float4 xv = ((const float4*)(x + (long)(R0 + row) * 256))[c4];
        _Float16* d = &xa[row * XS + c4 * 4];
        d[0] = (_Float16)xv.x; d[1] = (_Float16)xv.y;
        d[2] = (_Float16)xv.z; d[3] = (_Float16)xv.w;
    }
    __syncthreads();

    half8 af[8];
    #pragma unroll
    for (int kb = 0; kb < 8; ++kb)
        af[kb] = *(const half8*)&xa[(w * 16 + col) * XS + kb * 32 + quad * 8];

    int slm[4];
    #pragma unroll
    for (int mw = 0; mw < 4; ++mw) slm[mw] = __popc(col & TB.meas[mw]) & 1;

    float sS[4] = {0.f, 0.f, 0.f, 0.f};
    float sq[4][4] = {{0.f}};
    const _Float16* bre = Wt + (long)col * 256;
    const _Float16* bim = Wt + (long)(256 + col) * 256;

    #pragma unroll
    for (int c = 0; c < 16; ++c) {
        // split accumulators: 4 independent MFMA chains
        f32x4 cr0 = {0.f,0.f,0.f,0.f}, cr1 = {0.f,0.f,0.f,0.f};
        f32x4 ci0 = {0.f,0.f,0.f,0.f}, ci1 = {0.f,0.f,0.f,0.f};
        const long rowoff = (long)(c * 16) * 256 + quad * 8;
        #pragma unroll
        for (int kb = 0; kb < 4; ++kb) {
            const half8 br = *(const half8*)(bre + rowoff + kb * 32);
            cr0 = __builtin_amdgcn_mfma_f32_16x16x32_f16(af[kb], br, cr0, 0, 0, 0);
            const half8 bi = *(const half8*)(bim + rowoff + kb * 32);
            ci0 = __builtin_amdgcn_mfma_f32_16x16x32_f16(af[kb], bi, ci0, 0, 0, 0);
            const half8 br2 = *(const half8*)(bre + rowoff + (kb + 4) * 32);
            cr1 = __builtin_amdgcn_mfma_f32_16x16x32_f16(af[kb + 4], br2, cr1, 0, 0, 0);
            const half8 bi2 = *(const half8*)(bim + rowoff + (kb + 4) * 32);
            ci1 = __builtin_amdgcn_mfma_f32_16x16x32_f16(af[kb + 4], bi2, ci1, 0, 0, 0);
        }
        float sgn[4];
        #pragma unroll
        for (int mw = 0; mw < 4; ++mw) {
            const int scw = __builtin_popcount((c * 16) & TB.meas[mw]) & 1;  // folds
            sgn[mw] = (slm[mw] ^ scw) ? -1.f : 1.f;
        }
        #pragma unroll
        for (int r = 0; r < 4; ++r) {
            const float re = cr0[r] + cr1[r], im = ci0[r] + ci1[r];
            const float p = re * re + im * im;
            sS[r] += p;
            #pragma unroll
            for (int mw = 0; mw < 4; ++mw) sq[mw][r] = fmaf(sgn[mw], p, sq[mw][r]);
        }
    }

    // all-reduce across the 16-lane col dimension (i-columns)
    #pragma unroll
    for (int r = 0; r < 4; ++r) {
        sS[r] += lanex<1>(sS[r]); sS[r] += lanex<2>(sS[r]);
        sS[r] += lanex<4>(sS[r]); sS[r] += lanex<8>(sS[r]);
        #pragma unroll
        for (int mw = 0; mw < 4; ++mw) {
            sq[mw][r] += lanex<1>(sq[mw][r]); sq[mw][r] += lanex<2>(sq[mw][r]);
            sq[mw][r] += lanex<4>(sq[mw][r]); sq[mw][r] += lanex<8>(sq[mw][r]);
        }
    }

    __shared__ float hb[32][4];
    if (col == 0) {
        #pragma unroll
        for (int r = 0; r < 4; ++r) {
            const int mloc = w * 16 + quad * 4 + r;
            const int row = R0 + mloc;
            const float inv = 1.0f / sS[r];        // folds AmplitudeEmbedding norm
            float qe[4];
            #pragma unroll
            for (int mw = 0; mw < 4; ++mw) qe[mw] = sq[mw][r] * inv;
            const float4 cfv = ((const float4*)cfws)[row];
            const float cf[4] = {cfv.x, cfv.y, cfv.z, cfv.w};
            float h[4];
            #pragma unroll
            for (int kk = 0; kk < 4; ++kk) {
                float s = ab[kk] + cf[kk];
                #pragma unroll
                for (int j = 0; j < 4; ++j) s += aW[kk * 4 + j] * qe[j];
                h[kk] = s;
            }
            ((float4*)hws)[row] = make_float4(h[0], h[1], h[2], h[3]);
            hb[mloc][0] = h[0]; hb[mloc][1] = h[1];
            hb[mloc][2] = h[2]; hb[mloc][3] = h[3];
        }
    }
    __syncthreads();
    if (t < 20) {
        const int j = (t - 4) >> 2, kk = (t - 4) & 3;
        float v = 0.f;
        for (int rr = 0; rr < 32; ++rr)
            v += (t < 4) ? hb[rr][t] : hb[rr][j] * hb[rr][kk];
        atomicAdd(acc1 + (blockIdx.x & 31) * 20 + t, v);
    }
}

// ---------------------------------------------------------------------------
// k_mid: analytic BN1 + relu + layer2 -> z2; z2 batch stats.  (R0-verified)
// ---------------------------------------------------------------------------
__global__ __launch_bounds__(64) void k_mid(
        const float* __restrict__ hws, const float* __restrict__ acc1,
        const float* __restrict__ cW1, const float* __restrict__ cb1,
        const float* __restrict__ g1, const float* __restrict__ be1,
        const float* __restrict__ cW2, const float* __restrict__ cb2,
        float* __restrict__ z2ws, float* __restrict__ acc2) {
    const int t = threadIdx.x;
    __shared__ float sA[20];
    __shared__ float m1s[32], is1[32];
    if (t < 20) {
        float s = 0.f;
        for (int sl = 0; sl < 32; ++sl) s += acc1[sl * 20 + t];
        sA[t] = s;
    }
    __syncthreads();
    if (t < 32) {
        float mu[4], w[4];
        #pragma unroll
        for (int k = 0; k < 4; ++k) mu[k] = sA[k] * INV_B;
        float m = cb1[t];
        #pragma unroll
        for (int k = 0; k < 4; ++k) { w[k] = cW1[t * 4 + k]; m += w[k] * mu[k]; }
        float var = 0.f;
        #pragma unroll
        for (int a2 = 0; a2 < 4; ++a2)
            #pragma unroll
            for (int b2 = 0; b2 < 4; ++b2)
                var += w[a2] * w[b2] * (sA[4 + a2 * 4 + b2] * INV_B - mu[a2] * mu[b2]);
        m1s[t] = m;
        is1[t] = 1.0f / sqrtf(var + 1e-5f);
    }
    __syncthreads();

    const long e = (long)blockIdx.x * 64 + t;
    const float4 h4 = ((const float4*)hws)[e];
    const float h[4] = {h4.x, h4.y, h4.z, h4.w};
    float a1[32];
    #pragma unroll
    for (int j = 0; j < 32; ++j) {
        float zz = cb1[j];
        #pragma unroll
        for (int k = 0; k < 4; ++k) zz += cW1[j * 4 + k] * h[k];
        a1[j] = fmaxf((zz - m1s[j]) * is1[j] * g1[j] + be1[j], 0.f);
    }
    float z2[16];
    #pragma unroll
    for (int k = 0; k < 16; ++k) {
        float s = cb2[k];
        #pragma unroll
        for (int j = 0; j < 32; ++j) s += cW2[k * 32 + j] * a1[j];
        z2[k] = s;
    }
    float4* zp = (float4*)(z2ws + e * 16);
    zp[0] = make_float4(z2[0], z2[1], z2[2], z2[3]);
    zp[1] = make_float4(z2[4], z2[5], z2[6], z2[7]);
    zp[2] = make_float4(z2[8], z2[9], z2[10], z2[11]);
    zp[3] = make_float4(z2[12], z2[13], z2[14], z2[15]);

    float sv[16], sq2[16];
    #pragma unroll
    for (int k = 0; k < 16; ++k) { sv[k] = z2[k]; sq2[k] = z2[k] * z2[k]; }
    #pragma unroll
    for (int m = 1; m < 64; m <<= 1) {
        #pragma unroll
        for (int k = 0; k < 16; ++k) {
            sv[k] += __shfl_xor(sv[k], m, 64);
            sq2[k] += __shfl_xor(sq2[k], m, 64);
        }
    }
    if (t == 0) {
        float* dst = acc2 + ((int)blockIdx.x & 31) * 32;
        #pragma unroll
        for (int k = 0; k < 16; ++k) atomicAdd(dst + k, sv[k]);
        #pragma unroll
        for (int k = 0; k < 16; ++k) atomicAdd(dst + 16 + k, sq2[k]);
    }
}

// ---------------------------------------------------------------------------
// k_out: BN2 + relu + layer3(relu) + layer4 + sigmoid.  (R0-verified)
// ---------------------------------------------------------------------------
__global__ __launch_bounds__(64) void k_out(
        const float* __restrict__ z2ws, const float* __restrict__ acc2,
        const float* __restrict__ g2, const float* __restrict__ be2,
        const float* __restrict__ cW3, const float* __restrict__ cb3,
        const float* __restrict__ cW4, const float* __restrict__ cb4,
        float* __restrict__ out) {
    const int t = threadIdx.x;
    __shared__ float sB[32];
    __shared__ float m2s[16], is2[16];
    if (t < 32) {
        float s = 0.f;
        for (int sl = 0; sl < 32; ++sl) s += acc2[sl * 32 + t];
        sB[t] = s;
    }
    __syncthreads();
    if (t < 16) {
        const float m = sB[t] * INV_B;
        const float var = sB[16 + t] * INV_B - m * m;
        m2s[t] = m;
        is2[t] = 1.0f / sqrtf(var + 1e-5f);
    }
    __syncthreads();

    const long e = (long)blockIdx.x * 64 + t;
    const float4* zp = (const float4*)(z2ws + e * 16);
    const float4 v0 = zp[0], v1 = zp[1], v2 = zp[2], v3 = zp[3];
    const float z2[16] = {v0.x, v0.y, v0.z, v0.w, v1.x, v1.y, v1.z, v1.w,
                          v2.x, v2.y, v2.z, v2.w, v3.x, v3.y, v3.z, v3.w};
    float a2[16];
    #pragma unroll
    for (int k = 0; k < 16; ++k)
        a2[k] = fmaxf((z2[k] - m2s[k]) * is2[k] * g2[k] + be2[k], 0.f);
    float z3[8];
    #pragma unroll
    for (int j = 0; j < 8; ++j) {
        float s = cb3[j];
        #pragma unroll
        for (int k = 0; k < 16; ++k) s += cW3[j * 16 + k] * a2[k];
        z3[j] = fmaxf(s, 0.f);
    }
    float y = cb4[0];
    #pragma unroll
    for (int j = 0; j < 8; ++j) y += cW4[j] * z3[j];
    out[e] = 1.0f / (1.0f + expf(-y));
}

// ---------------------------------------------------------------------------
extern "C" void kernel_launch(void* const* d_in, const int* in_sizes, int n_in,
                              void* d_out, int out_size, void* d_ws, size_t ws_size,
                              hipStream_t stream) {
    (void)in_sizes; (void)n_in; (void)out_size; (void)ws_size;
    const float* x   = (const float*)d_in[0];
    const float* qw  = (const float*)d_in[1];
    const float* aW  = (const float*)d_in[2];
    const float* ab  = (const float*)d_in[3];
    const float* fW1 = (const float*)d_in[4];
    const float* fb1 = (const float*)d_in[5];
    const float* fW2 = (const float*)d_in[6];
    const float* fb2 = (const float*)d_in[7];
    const float* cW1 = (const float*)d_in[8];
    const float* cb1 = (const float*)d_in[9];
    const float* g1  = (const float*)d_in[10];
    const float* be1 = (const float*)d_in[11];
    const float* cW2 = (const float*)d_in[12];
    const float* cb2 = (const float*)d_in[13];
    const float* g2  = (const float*)d_in[14];
    const float* be2 = (const float*)d_in[15];
    const float* cW3 = (const float*)d_in[16];
    const float* cb3 = (const float*)d_in[17];
    const float* cW4 = (const float*)d_in[18];
    const float* cb4 = (const float*)d_in[19];

    float* ws   = (float*)d_ws;
    float* acc1 = ws;                    // 32 x 20 = 640   (zeroed by k_pre)
    float* acc2 = ws + 1024;             // 32 x 32 = 1024  (zeroed by k_pre)
    float* cfws = ws + 4096;             // 8192 x 4
    float* hws  = ws + 40960;            // 8192 x 4
    float* z2ws = ws + 81920;            // 8192 x 16
    _Float16* Wt = (_Float16*)(ws + 215040);  // 512 x 256 f16 = 256 KB

    k_pre <<<192, 256, 0, stream>>>(x, qw, fW1, fb1, fW2, fb2, Wt, cfws, ws);
    k_gemm<<<256, 128, 0, stream>>>(x, Wt, cfws, aW, ab, hws, acc1);
    k_mid <<<128, 64, 0, stream>>>(hws, acc1, cW1, cb1, g1, be1, cW2, cb2, z2ws, acc2);
    k_out <<<128, 64, 0, stream>>>(z2ws, acc2, g2, be2, cW3, cb3, cW4, cb4, (float*)d_out);
}